// Round 1
// baseline (91.427 us; speedup 1.0000x reference)
//
#include <hip/hip_runtime.h>

// TropicalLeNet fused: one block per batch element, all intermediates in LDS.
// Stages: minconv(5x5,pad=2)+avgpool -> maxconv(5x5,6->16)+avgpool -> FC 400->120->84->10
__global__ __launch_bounds__(256) void lenet_fused(
    const float* __restrict__ input,  // [256,1,28,28]
    const float* __restrict__ w1,     // [6,1,5,5]
    const float* __restrict__ w2,     // [16,6,5,5]
    const float* __restrict__ fw1,    // [120,400]
    const float* __restrict__ fb1,    // [120]
    const float* __restrict__ fw2,    // [84,120]
    const float* __restrict__ fb2,    // [84]
    const float* __restrict__ fw3,    // [10,84]
    const float* __restrict__ fb3,    // [10]
    float* __restrict__ out)          // [256,10]
{
    __shared__ float sIn[32 * 32];     // zero-padded input (pad=2 each side)
    __shared__ float sW1[150];         // 6*1*5*5
    __shared__ float sW2[2400];        // 16*6*5*5
    __shared__ float sX1[6 * 14 * 14]; // conv1+pool output
    __shared__ float sX2[400];         // conv2+pool output (flattened [16,5,5])
    __shared__ float sH1[120];
    __shared__ float sH2[84];

    const int tid = threadIdx.x;
    const int b = blockIdx.x;

    // ---- stage weights + zero-padded input into LDS ----
    for (int i = tid; i < 150; i += 256) sW1[i] = w1[i];
    for (int i = tid; i < 2400; i += 256) sW2[i] = w2[i];

    const float* inb = input + b * 784;
    for (int i = tid; i < 1024; i += 256) {
        int r = (i >> 5) - 2, c = (i & 31) - 2;
        float v = 0.f;
        if ((unsigned)r < 28u && (unsigned)c < 28u) v = inb[r * 28 + c];
        sIn[i] = v;  // zero padding: min-reduction sees 0 + w at borders, per jnp.pad
    }
    __syncthreads();

    // ---- conv1: min-plus, C=1, pad=2 -> 28x28; fused 2x2 avgpool -> [6,14,14] ----
    for (int idx = tid; idx < 6 * 14 * 14; idx += 256) {
        int o = idx / 196;
        int r = idx % 196;
        int ph = r / 14, pw = r % 14;
        const float* w = sW1 + o * 25;
        float acc = 0.f;
        #pragma unroll
        for (int dy = 0; dy < 2; ++dy) {
            #pragma unroll
            for (int dx = 0; dx < 2; ++dx) {
                int h = 2 * ph + dy, wc = 2 * pw + dx; // top-left in 32x32 padded frame
                float m = 1e30f;
                #pragma unroll
                for (int i = 0; i < 5; ++i) {
                    #pragma unroll
                    for (int j = 0; j < 5; ++j) {
                        m = fminf(m, sIn[(h + i) * 32 + (wc + j)] + w[i * 5 + j]);
                    }
                }
                acc += m;
            }
        }
        sX1[idx] = acc * 0.25f;
    }
    __syncthreads();

    // ---- conv2: max-plus over 6 channels, pad=0 -> 10x10; fused avgpool -> [16,5,5] ----
    for (int idx = tid; idx < 400; idx += 256) {
        int o = idx / 25;
        int r = idx % 25;
        int ph = r / 5, pw = r % 5;
        float acc = 0.f;
        #pragma unroll
        for (int dy = 0; dy < 2; ++dy) {
            #pragma unroll
            for (int dx = 0; dx < 2; ++dx) {
                int h = 2 * ph + dy, wc = 2 * pw + dx;
                float s = 0.f;
                for (int c = 0; c < 6; ++c) {
                    const float* x = sX1 + c * 196 + h * 14 + wc;
                    const float* w = sW2 + (o * 6 + c) * 25;
                    float m = -1e30f;
                    #pragma unroll
                    for (int i = 0; i < 5; ++i) {
                        #pragma unroll
                        for (int j = 0; j < 5; ++j) {
                            m = fmaxf(m, x[i * 14 + j] + w[i * 5 + j]);
                        }
                    }
                    s += m;
                }
                acc += s;
            }
        }
        sX2[idx] = acc * 0.25f;  // flat index o*25+ph*5+pw matches reshape [16,5,5]->400
    }
    __syncthreads();

    // ---- FC1: 400 -> 120, ReLU ----
    if (tid < 120) {
        const float* w = fw1 + tid * 400;
        float a0 = 0.f, a1 = 0.f, a2 = 0.f, a3 = 0.f;
        for (int k = 0; k < 400; k += 4) {
            a0 += sX2[k] * w[k];
            a1 += sX2[k + 1] * w[k + 1];
            a2 += sX2[k + 2] * w[k + 2];
            a3 += sX2[k + 3] * w[k + 3];
        }
        sH1[tid] = fmaxf((a0 + a1) + (a2 + a3) + fb1[tid], 0.f);
    }
    __syncthreads();

    // ---- FC2: 120 -> 84, ReLU ----
    if (tid < 84) {
        const float* w = fw2 + tid * 120;
        float acc = fb2[tid];
        for (int k = 0; k < 120; ++k) acc += sH1[k] * w[k];
        sH2[tid] = fmaxf(acc, 0.f);
    }
    __syncthreads();

    // ---- FC3: 84 -> 10 ----
    if (tid < 10) {
        const float* w = fw3 + tid * 84;
        float acc = fb3[tid];
        for (int k = 0; k < 84; ++k) acc += sH2[k] * w[k];
        out[b * 10 + tid] = acc;
    }
}

extern "C" void kernel_launch(void* const* d_in, const int* in_sizes, int n_in,
                              void* d_out, int out_size, void* d_ws, size_t ws_size,
                              hipStream_t stream) {
    const float* input = (const float*)d_in[0];
    const float* w1  = (const float*)d_in[1];
    const float* w2  = (const float*)d_in[2];
    const float* fw1 = (const float*)d_in[3];
    const float* fb1 = (const float*)d_in[4];
    const float* fw2 = (const float*)d_in[5];
    const float* fb2 = (const float*)d_in[6];
    const float* fw3 = (const float*)d_in[7];
    const float* fb3 = (const float*)d_in[8];
    float* out = (float*)d_out;

    lenet_fused<<<256, 256, 0, stream>>>(input, w1, w2, fw1, fb1, fw2, fb2,
                                         fw3, fb3, out);
}

// Round 2
// 86.804 us; speedup vs baseline: 1.0533x; 1.0533x over previous
//
#include <hip/hip_runtime.h>

// TropicalLeNet fully fused, one block (1024 thr = 16 waves) per batch image.
// Register-blocked column-strip min/max-plus convs; K-split FC layers.
// LDS arena unioned to stay under the 64 KB static-__shared__ limit.

#define POS_INF 1e30f

__global__ __launch_bounds__(1024, 4) void lenet_fused(
    const float* __restrict__ input,  // [256,1,28,28]
    const float* __restrict__ w1,     // [6,1,5,5]
    const float* __restrict__ w2,     // [16,6,5,5]
    const float* __restrict__ fw1,    // [120,400]
    const float* __restrict__ fb1,    // [120]
    const float* __restrict__ fw2,    // [84,120]
    const float* __restrict__ fb2,    // [84]
    const float* __restrict__ fw3,    // [10,84]
    const float* __restrict__ fb3,    // [10]
    float* __restrict__ out)          // [256,10]
{
    // ---- LDS arena (13930 floats = 55.7 KB) ----
    __shared__ float smem[13930];
    float* sW1 = smem;          // 150
    float* sW2 = smem + 150;    // 2400
    float* sX1 = smem + 2550;   // 6*14*14 = 1176 (conv1+pool out)
    float* sX2 = smem + 3726;   // 400 (conv2+pool out)
    float* sH1 = smem + 4126;   // 120
    float* sH2 = smem + 4246;   // 84
    float* A   = smem + 4330;   // union region, 9600 floats
    float* sIn = A;             // 1024 (32x32 padded input)   [phase 1]
    float* sP1 = A + 1024;      // 6*28*28 = 4704 (conv1 prepool) [phase 1]
    float* sP2 = A;             // 16*6*10*10 = 9600 (conv2 prepool) [phase 2]
    float* sR1 = A;             // 960 FC1 partials             [phase 3]
    float* sR2 = A + 960;       // 336 FC2 partials
    float* sR3 = A + 1296;      // 40  FC3 partials

    const int tid = threadIdx.x;
    const int b = blockIdx.x;

    // ---- stage: weights + zero-padded input ----
    if (tid < 150) sW1[tid] = w1[tid];
    for (int i = tid; i < 2400; i += 1024) sW2[i] = w2[i];
    {
        int r = (tid >> 5) - 2, c = (tid & 31) - 2;
        float v = 0.f;
        if ((unsigned)r < 28u && (unsigned)c < 28u) v = input[b * 784 + r * 28 + c];
        sIn[tid] = v; // zero pad: min sees 0 + w at borders (jnp.pad semantics)
    }
    __syncthreads();

    // ---- conv1 prepool: min-plus, items (o<6, rowgroup g<4, col j0<28) = 672 ----
    // thread owns a 7-row column strip; w1[o] in regs; x rows read once.
    if (tid < 672) {
        int o = tid / 112, rem = tid % 112, g = rem / 28, j0 = rem % 28;
        float w[25];
        #pragma unroll
        for (int k = 0; k < 25; ++k) w[k] = sW1[o * 25 + k];
        float acc[7];
        #pragma unroll
        for (int h = 0; h < 7; ++h) acc[h] = POS_INF;
        const float* xb = sIn + (7 * g) * 32 + j0;
        #pragma unroll
        for (int r = 0; r < 11; ++r) {
            float x0 = xb[r*32+0], x1 = xb[r*32+1], x2 = xb[r*32+2],
                  x3 = xb[r*32+3], x4 = xb[r*32+4];
            #pragma unroll
            for (int h = 0; h < 7; ++h) {
                if (h <= r && r <= h + 4) {            // compile-time pruned
                    const int i = r - h;
                    acc[h] = fminf(acc[h], x0 + w[i*5+0]);
                    acc[h] = fminf(acc[h], x1 + w[i*5+1]);
                    acc[h] = fminf(acc[h], x2 + w[i*5+2]);
                    acc[h] = fminf(acc[h], x3 + w[i*5+3]);
                    acc[h] = fminf(acc[h], x4 + w[i*5+4]);
                }
            }
        }
        #pragma unroll
        for (int h = 0; h < 7; ++h)
            sP1[(o * 28 + 7 * g + h) * 28 + j0] = acc[h];
    }
    __syncthreads();

    // ---- pool1 -> sX1 [6][14][14] ----
    for (int idx = tid; idx < 1176; idx += 1024) {
        int o = idx / 196, rem = idx % 196, ph = rem / 14, pw = rem % 14;
        const float* p = sP1 + (o * 28 + 2 * ph) * 28 + 2 * pw;
        sX1[idx] = 0.25f * (p[0] + p[1] + p[28] + p[29]);
    }
    __syncthreads();

    // ---- conv2 prepool: max-plus, items (o<16, c<6, col j0<10) = 960 ----
    if (tid < 960) {
        int o = tid / 60, rem = tid % 60, c = rem / 10, j0 = rem % 10;
        float w[25];
        #pragma unroll
        for (int k = 0; k < 25; ++k) w[k] = sW2[(o * 6 + c) * 25 + k];
        float acc[10];
        #pragma unroll
        for (int h = 0; h < 10; ++h) acc[h] = -POS_INF;
        const float* xb = sX1 + c * 196 + j0;
        #pragma unroll
        for (int r = 0; r < 14; ++r) {
            float x0 = xb[r*14+0], x1 = xb[r*14+1], x2 = xb[r*14+2],
                  x3 = xb[r*14+3], x4 = xb[r*14+4];
            #pragma unroll
            for (int h = 0; h < 10; ++h) {
                if (h <= r && r <= h + 4) {            // compile-time pruned
                    const int i = r - h;
                    acc[h] = fmaxf(acc[h], x0 + w[i*5+0]);
                    acc[h] = fmaxf(acc[h], x1 + w[i*5+1]);
                    acc[h] = fmaxf(acc[h], x2 + w[i*5+2]);
                    acc[h] = fmaxf(acc[h], x3 + w[i*5+3]);
                    acc[h] = fmaxf(acc[h], x4 + w[i*5+4]);
                }
            }
        }
        float* dst = sP2 + (o * 6 + c) * 100 + j0;
        #pragma unroll
        for (int h = 0; h < 10; ++h) dst[h * 10] = acc[h];
    }
    __syncthreads();

    // ---- pool2 + channel sum -> sX2[400] (flat [16][5][5]) ----
    if (tid < 400) {
        int o = tid / 25, rem = tid % 25, ph = rem / 5, pw = rem % 5;
        float s = 0.f;
        #pragma unroll
        for (int c = 0; c < 6; ++c) {
            const float* p = sP2 + (o * 6 + c) * 100 + (2 * ph) * 10 + 2 * pw;
            s += p[0] + p[1] + p[10] + p[11];
        }
        sX2[tid] = 0.25f * s;
    }
    __syncthreads();

    // ---- FC1: 120 outputs x 8-way K-split (960 threads, 50 MACs each) ----
    if (tid < 960) {
        int n = tid >> 3, s8 = tid & 7;
        const float* w = fw1 + n * 400 + s8 * 50;
        const float* x = sX2 + s8 * 50;
        float a = 0.f;
        #pragma unroll 10
        for (int k = 0; k < 50; ++k) a += x[k] * w[k];
        sR1[tid] = a;
    }
    __syncthreads();
    if (tid < 120) {
        const float* p = sR1 + tid * 8;
        float a = p[0]+p[1]+p[2]+p[3]+p[4]+p[5]+p[6]+p[7] + fb1[tid];
        sH1[tid] = fmaxf(a, 0.f);
    }
    __syncthreads();

    // ---- FC2: 84 outputs x 4-way K-split (336 threads, 30 MACs each) ----
    if (tid < 336) {
        int n = tid >> 2, s4 = tid & 3;
        const float* w = fw2 + n * 120 + s4 * 30;
        const float* x = sH1 + s4 * 30;
        float a = 0.f;
        #pragma unroll 10
        for (int k = 0; k < 30; ++k) a += x[k] * w[k];
        sR2[tid] = a;
    }
    __syncthreads();
    if (tid < 84) {
        const float* p = sR2 + tid * 4;
        sH2[tid] = fmaxf(p[0] + p[1] + p[2] + p[3] + fb2[tid], 0.f);
    }
    __syncthreads();

    // ---- FC3: 10 outputs x 4-way K-split (40 threads, 21 MACs each) ----
    if (tid < 40) {
        int n = tid >> 2, s4 = tid & 3;
        const float* w = fw3 + n * 84 + s4 * 21;
        const float* x = sH2 + s4 * 21;
        float a = 0.f;
        #pragma unroll 7
        for (int k = 0; k < 21; ++k) a += x[k] * w[k];
        sR3[tid] = a;
    }
    __syncthreads();
    if (tid < 10) {
        const float* p = sR3 + tid * 4;
        out[b * 10 + tid] = p[0] + p[1] + p[2] + p[3] + fb3[tid];
    }
}

extern "C" void kernel_launch(void* const* d_in, const int* in_sizes, int n_in,
                              void* d_out, int out_size, void* d_ws, size_t ws_size,
                              hipStream_t stream) {
    const float* input = (const float*)d_in[0];
    const float* w1  = (const float*)d_in[1];
    const float* w2  = (const float*)d_in[2];
    const float* fw1 = (const float*)d_in[3];
    const float* fb1 = (const float*)d_in[4];
    const float* fw2 = (const float*)d_in[5];
    const float* fb2 = (const float*)d_in[6];
    const float* fw3 = (const float*)d_in[7];
    const float* fb3 = (const float*)d_in[8];
    float* out = (float*)d_out;

    lenet_fused<<<256, 1024, 0, stream>>>(input, w1, w2, fw1, fb1, fw2, fb2,
                                          fw3, fb3, out);
}

// Round 3
// 85.474 us; speedup vs baseline: 1.0696x; 1.0156x over previous
//
#include <hip/hip_runtime.h>

// TropicalLeNet fully fused, one 1024-thread block (16 waves) per batch image.
// R3: conv2 o-paired + half-strip (fewer LDS reads/thread, VALU-bound),
//     FC reductions via __shfl_xor (3 fewer barriers, no LDS partials).

#define POS_INF 1e30f

__global__ __launch_bounds__(1024, 4) void lenet_fused(
    const float* __restrict__ input,  // [256,1,28,28]
    const float* __restrict__ w1,     // [6,1,5,5]
    const float* __restrict__ w2,     // [16,6,5,5]
    const float* __restrict__ fw1,    // [120,400]
    const float* __restrict__ fb1,    // [120]
    const float* __restrict__ fw2,    // [84,120]
    const float* __restrict__ fb2,    // [84]
    const float* __restrict__ fw3,    // [10,84]
    const float* __restrict__ fb3,    // [10]
    float* __restrict__ out)          // [256,10]
{
    // ---- LDS arena (13930 floats = 55.7 KB) ----
    __shared__ float smem[13930];
    float* sW1 = smem;          // 150
    float* sW2 = smem + 150;    // 2400
    float* sX1 = smem + 2550;   // 6*14*14 = 1176 (conv1+pool out)
    float* sX2 = smem + 3726;   // 400 (conv2+pool out)
    float* sH1 = smem + 4126;   // 120
    float* sH2 = smem + 4246;   // 84
    float* A   = smem + 4330;   // union region, 9600 floats
    float* sIn = A;             // 1024 (32x32 padded input)     [phase 1]
    float* sP1 = A + 1024;      // 6*28*28 = 4704 conv1 prepool  [phase 1]
    float* sP2 = A;             // 16*6*10*10 = 9600 conv2 prepool [phase 2]

    const int tid = threadIdx.x;
    const int b = blockIdx.x;

    // ---- stage: weights + zero-padded input ----
    if (tid < 150) sW1[tid] = w1[tid];
    for (int i = tid; i < 2400; i += 1024) sW2[i] = w2[i];
    {
        int r = (tid >> 5) - 2, c = (tid & 31) - 2;
        float v = 0.f;
        if ((unsigned)r < 28u && (unsigned)c < 28u) v = input[b * 784 + r * 28 + c];
        sIn[tid] = v; // zero pad: min sees 0 + w at borders (jnp.pad semantics)
    }
    __syncthreads();

    // ---- conv1 prepool: min-plus, items (o<6, rowgroup g<4, col j0<28) = 672 ----
    if (tid < 672) {
        int o = tid / 112, rem = tid % 112, g = rem / 28, j0 = rem % 28;
        float w[25];
        #pragma unroll
        for (int k = 0; k < 25; ++k) w[k] = sW1[o * 25 + k];
        float acc[7];
        #pragma unroll
        for (int h = 0; h < 7; ++h) acc[h] = POS_INF;
        const float* xb = sIn + (7 * g) * 32 + j0;
        #pragma unroll
        for (int r = 0; r < 11; ++r) {
            float x0 = xb[r*32+0], x1 = xb[r*32+1], x2 = xb[r*32+2],
                  x3 = xb[r*32+3], x4 = xb[r*32+4];
            #pragma unroll
            for (int h = 0; h < 7; ++h) {
                if (h <= r && r <= h + 4) {            // compile-time pruned
                    const int i = r - h;
                    acc[h] = fminf(acc[h], x0 + w[i*5+0]);
                    acc[h] = fminf(acc[h], x1 + w[i*5+1]);
                    acc[h] = fminf(acc[h], x2 + w[i*5+2]);
                    acc[h] = fminf(acc[h], x3 + w[i*5+3]);
                    acc[h] = fminf(acc[h], x4 + w[i*5+4]);
                }
            }
        }
        #pragma unroll
        for (int h = 0; h < 7; ++h)
            sP1[(o * 28 + 7 * g + h) * 28 + j0] = acc[h];
    }
    __syncthreads();

    // ---- pool1 -> sX1 [6][14][14] ----
    for (int idx = tid; idx < 1176; idx += 1024) {
        int o = idx / 196, rem = idx % 196, ph = rem / 14, pw = rem % 14;
        const float* p = sP1 + (o * 28 + 2 * ph) * 28 + 2 * pw;
        sX1[idx] = 0.25f * (p[0] + p[1] + p[28] + p[29]);
    }
    __syncthreads();

    // ---- conv2 prepool: max-plus. items (o-pair<8, c<6, j0<10, half<2) = 960 ----
    // Each thread: 2 output channels x 5 output rows x 1 column.
    // x rows h0..h0+8 read ONCE, shared across the o-pair (halves LDS traffic).
    if (tid < 960) {
        int o2 = tid / 120, rem = tid % 120;
        int c = rem / 20, rem2 = rem % 20;
        int j0 = rem2 >> 1, half = rem2 & 1;
        const int h0 = half * 5;
        const int oa = 2 * o2, ob = oa + 1;
        float wa[25], wb[25];
        #pragma unroll
        for (int k = 0; k < 25; ++k) wa[k] = sW2[(oa * 6 + c) * 25 + k];
        #pragma unroll
        for (int k = 0; k < 25; ++k) wb[k] = sW2[(ob * 6 + c) * 25 + k];
        float aa[5], ab[5];
        #pragma unroll
        for (int h = 0; h < 5; ++h) { aa[h] = -POS_INF; ab[h] = -POS_INF; }
        const float* xb = sX1 + c * 196 + j0;
        #pragma unroll
        for (int r = 0; r < 9; ++r) {               // input row = h0 + r
            const int row = (h0 + r) * 14;
            float x0 = xb[row+0], x1 = xb[row+1], x2 = xb[row+2],
                  x3 = xb[row+3], x4 = xb[row+4];
            #pragma unroll
            for (int h = 0; h < 5; ++h) {
                if (h <= r && r <= h + 4) {          // compile-time pruned
                    const int i = r - h;
                    aa[h] = fmaxf(aa[h], x0 + wa[i*5+0]);
                    aa[h] = fmaxf(aa[h], x1 + wa[i*5+1]);
                    aa[h] = fmaxf(aa[h], x2 + wa[i*5+2]);
                    aa[h] = fmaxf(aa[h], x3 + wa[i*5+3]);
                    aa[h] = fmaxf(aa[h], x4 + wa[i*5+4]);
                    ab[h] = fmaxf(ab[h], x0 + wb[i*5+0]);
                    ab[h] = fmaxf(ab[h], x1 + wb[i*5+1]);
                    ab[h] = fmaxf(ab[h], x2 + wb[i*5+2]);
                    ab[h] = fmaxf(ab[h], x3 + wb[i*5+3]);
                    ab[h] = fmaxf(ab[h], x4 + wb[i*5+4]);
                }
            }
        }
        float* da = sP2 + (oa * 6 + c) * 100 + j0;
        float* db = sP2 + (ob * 6 + c) * 100 + j0;
        #pragma unroll
        for (int h = 0; h < 5; ++h) {
            da[(h0 + h) * 10] = aa[h];
            db[(h0 + h) * 10] = ab[h];
        }
    }
    __syncthreads();

    // ---- pool2 + channel sum -> sX2[400] (flat [16][5][5]) ----
    if (tid < 400) {
        int o = tid / 25, rem = tid % 25, ph = rem / 5, pw = rem % 5;
        float s = 0.f;
        #pragma unroll
        for (int c = 0; c < 6; ++c) {
            const float* p = sP2 + (o * 6 + c) * 100 + (2 * ph) * 10 + 2 * pw;
            s += p[0] + p[1] + p[10] + p[11];
        }
        sX2[tid] = 0.25f * s;
    }
    __syncthreads();

    // ---- FC1: 120 outputs x 8-way K-split, shuffle reduce ----
    if (tid < 960) {
        int n = tid >> 3, s8 = tid & 7;
        const float* w = fw1 + n * 400 + s8 * 50;
        const float* x = sX2 + s8 * 50;
        float a = 0.f;
        #pragma unroll 10
        for (int k = 0; k < 50; ++k) a += x[k] * w[k];
        a += __shfl_xor(a, 1, 8);
        a += __shfl_xor(a, 2, 8);
        a += __shfl_xor(a, 4, 8);
        if (s8 == 0) sH1[n] = fmaxf(a + fb1[n], 0.f);
    }
    __syncthreads();

    // ---- FC2: 84 outputs x 4-way K-split, shuffle reduce ----
    if (tid < 336) {
        int n = tid >> 2, s4 = tid & 3;
        const float* w = fw2 + n * 120 + s4 * 30;
        const float* x = sH1 + s4 * 30;
        float a = 0.f;
        #pragma unroll 10
        for (int k = 0; k < 30; ++k) a += x[k] * w[k];
        a += __shfl_xor(a, 1, 4);
        a += __shfl_xor(a, 2, 4);
        if (s4 == 0) sH2[n] = fmaxf(a + fb2[n], 0.f);
    }
    __syncthreads();

    // ---- FC3: 10 outputs x 4-way K-split, shuffle reduce ----
    if (tid < 40) {
        int n = tid >> 2, s4 = tid & 3;
        const float* w = fw3 + n * 84 + s4 * 21;
        const float* x = sH2 + s4 * 21;
        float a = 0.f;
        #pragma unroll 7
        for (int k = 0; k < 21; ++k) a += x[k] * w[k];
        a += __shfl_xor(a, 1, 4);
        a += __shfl_xor(a, 2, 4);
        if (s4 == 0) out[b * 10 + n] = a + fb3[n];
    }
}

extern "C" void kernel_launch(void* const* d_in, const int* in_sizes, int n_in,
                              void* d_out, int out_size, void* d_ws, size_t ws_size,
                              hipStream_t stream) {
    const float* input = (const float*)d_in[0];
    const float* w1  = (const float*)d_in[1];
    const float* w2  = (const float*)d_in[2];
    const float* fw1 = (const float*)d_in[3];
    const float* fb1 = (const float*)d_in[4];
    const float* fw2 = (const float*)d_in[5];
    const float* fb2 = (const float*)d_in[6];
    const float* fw3 = (const float*)d_in[7];
    const float* fb3 = (const float*)d_in[8];
    float* out = (float*)d_out;

    lenet_fused<<<256, 1024, 0, stream>>>(input, w1, w2, fw1, fb1, fw2, fb2,
                                          fw3, fb3, out);
}

// Round 4
// 79.173 us; speedup vs baseline: 1.1548x; 1.0796x over previous
//
#include <hip/hip_runtime.h>

// TropicalLeNet fused, one 1024-thread block per image.
// R4: shift-replicated LDS tiles -> ds_read_b128 window loads; pool1 fused
// into conv1 (sP1 eliminated); padded weight stride 28 for b128 reads;
// float4 FC1/FC2. Static LDS 63.04 KB (< 64 KB limit).

#define POS_INF 1e30f

__global__ __launch_bounds__(1024) void lenet_fused(
    const float* __restrict__ input,  // [256,1,28,28]
    const float* __restrict__ w1,     // [6,1,5,5]
    const float* __restrict__ w2,     // [16,6,5,5]
    const float* __restrict__ fw1,    // [120,400]
    const float* __restrict__ fb1,    // [120]
    const float* __restrict__ fw2,    // [84,120]
    const float* __restrict__ fb2,    // [84]
    const float* __restrict__ fw3,    // [10,84]
    const float* __restrict__ fb3,    // [10]
    float* __restrict__ out)          // [256,10]
{
    // ---- LDS arena: 15760 floats = 63.04 KB ----
    __shared__ float smem[15760];
    float* sW1p = smem;           // 6*28 = 168 (pad 176)  w1 padded stride 28
    float* sW2p = smem + 176;     // 96*28 = 2688          w2 padded stride 28
    float* sX1c = smem + 2864;    // 2 shifted copies [2][6][14][16] = 2688
    float* sX2  = smem + 5552;    // 400
    float* sH1  = smem + 5952;    // 120
    float* sH2  = smem + 6072;    // 84 (pad 88)
    float* A    = smem + 6160;    // 9600-float union
    float* sIn  = A;              // [2][32][32] shifted padded input (phase 1)
    float* sP2  = A;              // [16*6][10][10] conv2 prepool (phase 2)

    const int tid = threadIdx.x;
    const int b = blockIdx.x;

    // ---- stage: padded weights + 2 shifted copies of zero-padded input ----
    if (tid < 150) sW1p[(tid / 25) * 28 + tid % 25] = w1[tid];
    for (int i = tid; i < 2400; i += 1024)
        sW2p[(i / 25) * 28 + (i % 25)] = w2[i];
    {
        int r = tid >> 5, cc = tid & 31;
        const float* inb = input + b * 784;
        float v0 = 0.f, v1 = 0.f;
        if (r >= 2 && r < 30) {
            if (cc >= 2 && cc < 30) v0 = inb[(r - 2) * 28 + (cc - 2)]; // shift 0
            if (cc < 28)            v1 = inb[(r - 2) * 28 + cc];       // shift 2
        }
        sIn[tid] = v0;          // copy0[c] = xpad[c]
        sIn[1024 + tid] = v1;   // copy1[c] = xpad[c+2]
    }
    __syncthreads();

    // ---- conv1 (min-plus, pad=2) + pool1 fused: (o<6, g<7, jp<14) = 588 thr ----
    // thread: conv rows 4g..4g+3, conv cols J,J+1 -> pooled (2g,jp),(2g+1,jp)
    if (tid < 588) {
        int o = tid / 98, rem = tid % 98;
        int g = rem / 14, jp = rem % 14;
        const int J = 2 * jp;
        const int s = J & 3;                    // 0 or 2
        const float* xbase = sIn + (s >> 1) * 1024 + (J - s);
        float w[25];
        #pragma unroll
        for (int q = 0; q < 6; ++q) {
            float4 t = ((const float4*)(sW1p + o * 28))[q];
            w[4*q] = t.x; w[4*q+1] = t.y; w[4*q+2] = t.z; w[4*q+3] = t.w;
        }
        w[24] = sW1p[o * 28 + 24];
        float accA[4], accB[4];
        #pragma unroll
        for (int h = 0; h < 4; ++h) { accA[h] = POS_INF; accB[h] = POS_INF; }
        #pragma unroll
        for (int ir = 0; ir < 8; ++ir) {        // input rows 4g+ir
            const float* row = xbase + (4 * g + ir) * 32;
            float4 xa = ((const float4*)row)[0];
            float4 xb = ((const float4*)row)[1];
            float x[8] = {xa.x, xa.y, xa.z, xa.w, xb.x, xb.y, xb.z, xb.w};
            // x[t] = xpad[J + t]
            #pragma unroll
            for (int h = 0; h < 4; ++h) {
                if (ir >= h && ir <= h + 4) {   // compile-time pruned
                    const int i = ir - h;
                    #pragma unroll
                    for (int j = 0; j < 5; ++j) {
                        accA[h] = fminf(accA[h], x[j]     + w[i*5+j]);
                        accB[h] = fminf(accB[h], x[j + 1] + w[i*5+j]);
                    }
                }
            }
        }
        float p0 = 0.25f * (accA[0] + accB[0] + accA[1] + accB[1]);
        float p1 = 0.25f * (accA[2] + accB[2] + accA[3] + accB[3]);
        // write into both shifted copies: copy ci holds X1[.][.][col+2ci]
        #pragma unroll
        for (int ci = 0; ci < 2; ++ci) {
            int col = jp - 2 * ci;
            if (col >= 0) {
                float* dst = sX1c + ci * 1344 + o * 224 + (2 * g) * 16 + col;
                dst[0]  = p0;   // pooled row 2g
                dst[16] = p1;   // pooled row 2g+1
            }
        }
    }
    __syncthreads();

    // ---- conv2 prepool (max-plus): (o2<8, c<6, jp<5, half<2) = 480 thr ----
    // thread: 2 out channels x 2 cols (j0,j0+1) x 5 out rows
    if (tid < 480) {
        int o2 = tid / 60, rem = tid % 60;
        int c = rem / 10, r2 = rem % 10;
        int jp = r2 >> 1, half = r2 & 1;
        const int j0 = 2 * jp;                  // 0,2,4,6,8
        const int s = j0 & 3;                   // 0 or 2
        const int h0 = 5 * half;
        const int oa = 2 * o2;
        float wa[25], wb[25];
        #pragma unroll
        for (int q = 0; q < 6; ++q) {
            float4 t = ((const float4*)(sW2p + (oa * 6 + c) * 28))[q];
            wa[4*q] = t.x; wa[4*q+1] = t.y; wa[4*q+2] = t.z; wa[4*q+3] = t.w;
            float4 u = ((const float4*)(sW2p + ((oa + 1) * 6 + c) * 28))[q];
            wb[4*q] = u.x; wb[4*q+1] = u.y; wb[4*q+2] = u.z; wb[4*q+3] = u.w;
        }
        wa[24] = sW2p[(oa * 6 + c) * 28 + 24];
        wb[24] = sW2p[((oa + 1) * 6 + c) * 28 + 24];
        float aa0[5], aa1[5], ab0[5], ab1[5];
        #pragma unroll
        for (int h = 0; h < 5; ++h) {
            aa0[h] = -POS_INF; aa1[h] = -POS_INF;
            ab0[h] = -POS_INF; ab1[h] = -POS_INF;
        }
        const float* xbase = sX1c + (s >> 1) * 1344 + c * 224 + (j0 - s);
        #pragma unroll
        for (int r = 0; r < 9; ++r) {           // input rows h0+r
            const float* row = xbase + (h0 + r) * 16;
            float4 xa = ((const float4*)row)[0];
            float4 xb = ((const float4*)row)[1];
            float x[8] = {xa.x, xa.y, xa.z, xa.w, xb.x, xb.y, xb.z, xb.w};
            // x[t] = X1[c][h0+r][j0+t]; x[6..7] unused padding
            #pragma unroll
            for (int h = 0; h < 5; ++h) {
                if (r >= h && r <= h + 4) {     // compile-time pruned
                    const int i = r - h;
                    #pragma unroll
                    for (int j = 0; j < 5; ++j) {
                        const float va = wa[i*5+j], vb = wb[i*5+j];
                        aa0[h] = fmaxf(aa0[h], x[j]     + va);
                        aa1[h] = fmaxf(aa1[h], x[j + 1] + va);
                        ab0[h] = fmaxf(ab0[h], x[j]     + vb);
                        ab1[h] = fmaxf(ab1[h], x[j + 1] + vb);
                    }
                }
            }
        }
        float* da = sP2 + (oa * 6 + c) * 100 + j0;
        float* db = sP2 + ((oa + 1) * 6 + c) * 100 + j0;
        #pragma unroll
        for (int h = 0; h < 5; ++h) {
            da[(h0 + h) * 10]     = aa0[h];
            da[(h0 + h) * 10 + 1] = aa1[h];
            db[(h0 + h) * 10]     = ab0[h];
            db[(h0 + h) * 10 + 1] = ab1[h];
        }
    }
    __syncthreads();

    // ---- pool2 + channel sum -> sX2[400] (flat [16][5][5]) ----
    if (tid < 400) {
        int o = tid / 25, rem = tid % 25, ph = rem / 5, pw = rem % 5;
        float s = 0.f;
        #pragma unroll
        for (int c = 0; c < 6; ++c) {
            const float* p = sP2 + (o * 6 + c) * 100 + 2 * ph * 10 + 2 * pw;
            float2 u = *(const float2*)p;
            float2 v = *(const float2*)(p + 10);
            s += u.x + u.y + v.x + v.y;
        }
        sX2[tid] = 0.25f * s;
    }
    __syncthreads();

    // ---- FC1: 120 x 4-way float4-split (480 thr), shfl reduce ----
    if (tid < 480) {
        int n = tid >> 2, s4 = tid & 3;
        const float4* wrow = (const float4*)(fw1 + n * 400);
        const float4* xv = (const float4*)sX2;
        float a = 0.f;
        #pragma unroll
        for (int i = 0; i < 25; ++i) {
            int j = s4 + 4 * i;
            float4 wv = wrow[j];
            float4 x4 = xv[j];
            a += wv.x * x4.x + wv.y * x4.y + wv.z * x4.z + wv.w * x4.w;
        }
        a += __shfl_xor(a, 1, 4);
        a += __shfl_xor(a, 2, 4);
        if (s4 == 0) sH1[n] = fmaxf(a + fb1[n], 0.f);
    }
    __syncthreads();

    // ---- FC2: 84 x 2-way float4-split (168 thr), shfl reduce ----
    if (tid < 168) {
        int n = tid >> 1, s2 = tid & 1;
        const float4* wrow = (const float4*)(fw2 + n * 120);
        const float4* xv = (const float4*)sH1;
        float a = 0.f;
        #pragma unroll
        for (int i = 0; i < 15; ++i) {
            int j = s2 + 2 * i;
            float4 wv = wrow[j];
            float4 x4 = xv[j];
            a += wv.x * x4.x + wv.y * x4.y + wv.z * x4.z + wv.w * x4.w;
        }
        a += __shfl_xor(a, 1, 2);
        if (s2 == 0) sH2[n] = fmaxf(a + fb2[n], 0.f);
    }
    __syncthreads();

    // ---- FC3: 10 x 4-way K-split (40 thr), shfl reduce ----
    if (tid < 40) {
        int n = tid >> 2, s4 = tid & 3;
        const float* w = fw3 + n * 84 + s4 * 21;
        const float* x = sH2 + s4 * 21;
        float a = 0.f;
        #pragma unroll 7
        for (int k = 0; k < 21; ++k) a += x[k] * w[k];
        a += __shfl_xor(a, 1, 4);
        a += __shfl_xor(a, 2, 4);
        if (s4 == 0) out[b * 10 + n] = a + fb3[n];
    }
}

extern "C" void kernel_launch(void* const* d_in, const int* in_sizes, int n_in,
                              void* d_out, int out_size, void* d_ws, size_t ws_size,
                              hipStream_t stream) {
    const float* input = (const float*)d_in[0];
    const float* w1  = (const float*)d_in[1];
    const float* w2  = (const float*)d_in[2];
    const float* fw1 = (const float*)d_in[3];
    const float* fb1 = (const float*)d_in[4];
    const float* fw2 = (const float*)d_in[5];
    const float* fb2 = (const float*)d_in[6];
    const float* fw3 = (const float*)d_in[7];
    const float* fb3 = (const float*)d_in[8];
    float* out = (float*)d_out;

    lenet_fused<<<256, 1024, 0, stream>>>(input, w1, w2, fw1, fb1, fw2, fb2,
                                          fw3, fb3, out);
}